// Round 8
// baseline (1478.335 us; speedup 1.0000x reference)
//
#include <hip/hip_runtime.h>

#define N 4096
#define D 64
#define TCAP 1024
#define TTHRESH 96
#define SNB 256
#define SNT 512
#define RPAIRS 12

typedef unsigned long long u64;

// ---- persistent device state (no full cost matrix: costs are recomputed) ----
__device__ float g_tailC[(size_t)TCAP * TCAP]; // 4 MB dense tail matrix
__device__ float g_x2[N], g_y2[N];
__device__ int   g_rowMatch[N];
__device__ int   g_freeRows[2][N];
__device__ int   g_freeCols[2][N];
__device__ int   g_rowBestJ[N];
__device__ u64   g_colMin[2][N];
__device__ int   g_nr[2], g_nc[2];
__device__ int   g_done, g_finalCur;

__device__ inline u64 shfl_down_u64(u64 v, int d) {
  unsigned lo = (unsigned)(v & 0xffffffffull);
  unsigned hi = (unsigned)(v >> 32);
  lo = __shfl_down(lo, d, 64);
  hi = __shfl_down(hi, d, 64);
  return ((u64)hi << 32) | (u64)lo;
}

// 512-thread (8-wave) block min-reduce of per-thread best[r], r < rows <= 8.
// Result for row r in s_part[128 + r].
__device__ inline void block_rowmin_reduce8(u64* best, int rows, u64* s_part) {
  const int tid = threadIdx.x;
  const int lane = tid & 63;
  const int wv = tid >> 6;
#pragma unroll
  for (int r = 0; r < 8; ++r) {
    if (r < rows) {
      u64 v = best[r];
#pragma unroll
      for (int d = 32; d > 0; d >>= 1) {
        u64 o = shfl_down_u64(v, d);
        v = (o < v) ? o : v;
      }
      if (lane == 0) s_part[r * 8 + wv] = v;
    }
  }
  __syncthreads();
  if (tid < rows) {
    u64 mn = s_part[tid * 8];
#pragma unroll
    for (int w = 1; w < 8; ++w) {
      u64 o = s_part[tid * 8 + w];
      mn = (o < mn) ? o : mn;
    }
    s_part[128 + tid] = mn;
  }
}

// Exact cost chain (identical in every phase): kc-ascending fmaf x/y/z/w,
// then fl(fl(x2+y2) - 2*acc), clamp, sqrt.
__device__ inline float cost_eval(float acc, float x2r, float y2j) {
  float t = __fadd_rn(x2r, y2j);
  float sq = __fsub_rn(t, __fmul_rn(2.0f, acc));
  sq = fmaxf(sq, 0.0f);
  return __fsqrt_rn(sq);
}

// ================= init: x2/y2 + state reset =================
__global__ void __launch_bounds__(256) k_init(const float* __restrict__ x,
                                              const float* __restrict__ y) {
  const int i = blockIdx.x * 256 + threadIdx.x;  // grid = 16 blocks -> 4096
  // numpy pairwise_sum order for n=64: 8 accumulators, then
  // ((r0+r1)+(r2+r3)) + ((r4+r5)+(r6+r7)). No FMA contraction.
  const float* xr = x + (size_t)i * D;
  const float* yr = y + (size_t)i * D;
  float qx[8], qy[8];
#pragma unroll
  for (int j = 0; j < 8; ++j) {
    float v = xr[j]; qx[j] = __fmul_rn(v, v);
    float w = yr[j]; qy[j] = __fmul_rn(w, w);
  }
#pragma unroll
  for (int m = 8; m < D; m += 8) {
#pragma unroll
    for (int j = 0; j < 8; ++j) {
      float v = xr[m + j]; qx[j] = __fadd_rn(qx[j], __fmul_rn(v, v));
      float w = yr[m + j]; qy[j] = __fadd_rn(qy[j], __fmul_rn(w, w));
    }
  }
  g_x2[i] = __fadd_rn(__fadd_rn(__fadd_rn(qx[0], qx[1]), __fadd_rn(qx[2], qx[3])),
                      __fadd_rn(__fadd_rn(qx[4], qx[5]), __fadd_rn(qx[6], qx[7])));
  g_y2[i] = __fadd_rn(__fadd_rn(__fadd_rn(qy[0], qy[1]), __fadd_rn(qy[2], qy[3])),
                      __fadd_rn(__fadd_rn(qy[4], qy[5]), __fadd_rn(qy[6], qy[7])));
  g_rowMatch[i] = -1;
  g_freeRows[0][i] = i;
  g_freeCols[0][i] = i;
  g_colMin[0][i] = ~0ull;
  g_colMin[1][i] = ~0ull;
  if (i == 0) {
    g_nr[0] = N; g_nc[0] = N; g_nr[1] = 0; g_nc[1] = 0;
    g_done = 0;
    g_finalCur = ((RPAIRS & 1) ^ 1);  // fallback parity if g_done never fires
  }
}

// ================= round 0: cost recompute + row/col minima =================
// 8 rows x 4 cols per thread, 2 column passes.
// __launch_bounds__(512, 2): min 2 waves/EU -> 256-VGPR cap. Demand ~160;
// the default 128 cap forced ~100 MB/dispatch of scratch spill (r6/r7 PMC).
__global__ void __launch_bounds__(SNT, 2) k_scan0(const float* __restrict__ x,
                                                  const float* __restrict__ y) {
  __shared__ u64 s_part[128 + 16];
  const int tid = threadIdx.x;
  const int r0 = blockIdx.x << 3;  // 512 blocks x 8 rows

  float x2r[8];
#pragma unroll
  for (int r = 0; r < 8; ++r) x2r[r] = g_x2[r0 + r];
  u64 best[8];
#pragma unroll
  for (int r = 0; r < 8; ++r) best[r] = ~0ull;

#pragma unroll
  for (int q = 0; q < 2; ++q) {
    const int c0 = tid + (q << 11);  // cols c0 + 512*k, k=0..3
    float acc[8][4];
#pragma unroll
    for (int r = 0; r < 8; ++r)
#pragma unroll
      for (int k = 0; k < 4; ++k) acc[r][k] = 0.0f;

    const float4* yb0 = reinterpret_cast<const float4*>(y + (size_t)c0 * D);
    const float4* yb1 = reinterpret_cast<const float4*>(y + (size_t)(c0 + 512) * D);
    const float4* yb2 = reinterpret_cast<const float4*>(y + (size_t)(c0 + 1024) * D);
    const float4* yb3 = reinterpret_cast<const float4*>(y + (size_t)(c0 + 1536) * D);
#pragma unroll
    for (int kc = 0; kc < 16; ++kc) {
      float4 yv0 = yb0[kc], yv1 = yb1[kc], yv2 = yb2[kc], yv3 = yb3[kc];
#pragma unroll
      for (int r = 0; r < 8; ++r) {
        float4 xv = reinterpret_cast<const float4*>(x + (size_t)(r0 + r) * D)[kc];  // wave-uniform
        acc[r][0] = fmaf(xv.x, yv0.x, acc[r][0]);
        acc[r][0] = fmaf(xv.y, yv0.y, acc[r][0]);
        acc[r][0] = fmaf(xv.z, yv0.z, acc[r][0]);
        acc[r][0] = fmaf(xv.w, yv0.w, acc[r][0]);
        acc[r][1] = fmaf(xv.x, yv1.x, acc[r][1]);
        acc[r][1] = fmaf(xv.y, yv1.y, acc[r][1]);
        acc[r][1] = fmaf(xv.z, yv1.z, acc[r][1]);
        acc[r][1] = fmaf(xv.w, yv1.w, acc[r][1]);
        acc[r][2] = fmaf(xv.x, yv2.x, acc[r][2]);
        acc[r][2] = fmaf(xv.y, yv2.y, acc[r][2]);
        acc[r][2] = fmaf(xv.z, yv2.z, acc[r][2]);
        acc[r][2] = fmaf(xv.w, yv2.w, acc[r][2]);
        acc[r][3] = fmaf(xv.x, yv3.x, acc[r][3]);
        acc[r][3] = fmaf(xv.y, yv3.y, acc[r][3]);
        acc[r][3] = fmaf(xv.z, yv3.z, acc[r][3]);
        acc[r][3] = fmaf(xv.w, yv3.w, acc[r][3]);
      }
    }
#pragma unroll
    for (int k = 0; k < 4; ++k) {
      const int c = c0 + (k << 9);
      const float y2j = g_y2[c];
      u64 ckey = ~0ull;
#pragma unroll
      for (int r = 0; r < 8; ++r) {
        float cost = cost_eval(acc[r][k], x2r[r], y2j);
        u64 cb = ((u64)__float_as_uint(cost)) << 32;
        u64 rk = cb | (unsigned)c;
        best[r] = (rk < best[r]) ? rk : best[r];
        u64 ck = cb | (unsigned)(r0 + r);
        ckey = (ck < ckey) ? ck : ckey;
      }
      u64 curv = g_colMin[0][c];  // stale reads only ever too-high: safe filter
      if (ckey < curv) atomicMin((unsigned long long*)&g_colMin[0][c], ckey);
    }
  }

  block_rowmin_reduce8(best, 8, s_part);
  if (tid < 8) g_rowBestJ[r0 + tid] = (int)(s_part[128 + tid] & 0xffffffffull);
}

// ================= rounds >= 1: recompute scan over free rows/cols ===========
// 8-row groups, group-stride loop. Same 256-VGPR headroom as k_scan0.
__global__ void __launch_bounds__(SNT, 2) k_scanN(const float* __restrict__ x,
                                                  const float* __restrict__ y, int round) {
  if (g_done) return;
  const int cur = round & 1;
  const int nr = g_nr[cur], nc = g_nc[cur];
  const int tid = threadIdx.x, bid = blockIdx.x;
  const int ngroups = (nr + 7) >> 3;
  __shared__ u64 s_part[128 + 16];
  __shared__ int s_irow[8];
  const int j0 = g_freeCols[cur][0];

  for (int g = bid; g < ngroups; g += SNB) {
    __syncthreads();  // protect s_irow/s_part reuse across group iterations
    const int r0 = g << 3;
    const int rows = min(8, nr - r0);
    if (tid < 8) {
      int rr = (tid < rows) ? (r0 + tid) : r0;
      s_irow[tid] = g_freeRows[cur][rr];
    }
    __syncthreads();

    int ir[8]; float x2r[8];
#pragma unroll
    for (int r = 0; r < 8; ++r) { ir[r] = s_irow[r]; x2r[r] = g_x2[ir[r]]; }
    u64 best[8];
#pragma unroll
    for (int r = 0; r < 8; ++r) best[r] = ~0ull;

    for (int cbase = tid; cbase < nc; cbase += (SNT << 2)) {
      int jj[4];
#pragma unroll
      for (int k = 0; k < 4; ++k) {
        int c = cbase + (k << 9);
        jj[k] = (c < nc) ? g_freeCols[cur][c] : j0;  // pad with valid col, masked later
      }
      float acc[8][4];
#pragma unroll
      for (int r = 0; r < 8; ++r)
#pragma unroll
        for (int k = 0; k < 4; ++k) acc[r][k] = 0.0f;

      const float4* yb0 = reinterpret_cast<const float4*>(y + (size_t)jj[0] * D);
      const float4* yb1 = reinterpret_cast<const float4*>(y + (size_t)jj[1] * D);
      const float4* yb2 = reinterpret_cast<const float4*>(y + (size_t)jj[2] * D);
      const float4* yb3 = reinterpret_cast<const float4*>(y + (size_t)jj[3] * D);
#pragma unroll
      for (int kc = 0; kc < 16; ++kc) {
        float4 yv0 = yb0[kc], yv1 = yb1[kc], yv2 = yb2[kc], yv3 = yb3[kc];
#pragma unroll
        for (int r = 0; r < 8; ++r) {
          float4 xv = reinterpret_cast<const float4*>(x + (size_t)ir[r] * D)[kc];  // wave-uniform
          acc[r][0] = fmaf(xv.x, yv0.x, acc[r][0]);
          acc[r][0] = fmaf(xv.y, yv0.y, acc[r][0]);
          acc[r][0] = fmaf(xv.z, yv0.z, acc[r][0]);
          acc[r][0] = fmaf(xv.w, yv0.w, acc[r][0]);
          acc[r][1] = fmaf(xv.x, yv1.x, acc[r][1]);
          acc[r][1] = fmaf(xv.y, yv1.y, acc[r][1]);
          acc[r][1] = fmaf(xv.z, yv1.z, acc[r][1]);
          acc[r][1] = fmaf(xv.w, yv1.w, acc[r][1]);
          acc[r][2] = fmaf(xv.x, yv2.x, acc[r][2]);
          acc[r][2] = fmaf(xv.y, yv2.y, acc[r][2]);
          acc[r][2] = fmaf(xv.z, yv2.z, acc[r][2]);
          acc[r][2] = fmaf(xv.w, yv2.w, acc[r][2]);
          acc[r][3] = fmaf(xv.x, yv3.x, acc[r][3]);
          acc[r][3] = fmaf(xv.y, yv3.y, acc[r][3]);
          acc[r][3] = fmaf(xv.z, yv3.z, acc[r][3]);
          acc[r][3] = fmaf(xv.w, yv3.w, acc[r][3]);
        }
      }
#pragma unroll
      for (int k = 0; k < 4; ++k) {
        if (cbase + (k << 9) < nc) {
          const int j = jj[k];
          const float y2j = g_y2[j];
          u64 ckey = ~0ull;
#pragma unroll
          for (int r = 0; r < 8; ++r) {
            if (r < rows) {
              float cost = cost_eval(acc[r][k], x2r[r], y2j);
              u64 cb = ((u64)__float_as_uint(cost)) << 32;
              u64 rk = cb | (unsigned)j;
              best[r] = (rk < best[r]) ? rk : best[r];
              u64 ck = cb | (unsigned)ir[r];
              ckey = (ck < ckey) ? ck : ckey;
            }
          }
          u64 curv = g_colMin[cur][j];
          if (ckey < curv) atomicMin((unsigned long long*)&g_colMin[cur][j], ckey);
        }
      }
    }

    block_rowmin_reduce8(best, rows, s_part);
    if (tid < rows) g_rowBestJ[s_irow[tid]] = (int)(s_part[128 + tid] & 0xffffffffull);
  }
}

// ================= match + rebuild free lists =================
__global__ void __launch_bounds__(SNT) k_match(int round) {
  if (g_done) return;
  const int cur = round & 1, nxt = cur ^ 1;
  const int tid = threadIdx.x, bid = blockIdx.x;
  const int nr = g_nr[cur], nc = g_nc[cur];
  __shared__ int s_wc[8];
  __shared__ int s_base;

  if (bid >= 2) {  // reset colMin buffer for round+1
    for (int t = (bid - 2) * SNT + tid; t < N; t += (SNB - 2) * SNT)
      g_colMin[nxt][t] = ~0ull;
    return;
  }

  const int lane = tid & 63, wv = tid >> 6;
  if (bid == 0) {  // rows: write matches + ordered compaction
    if (tid == 0) s_base = 0;
    __syncthreads();
    for (int start = 0; start < nr; start += SNT) {
      int r = start + tid;
      int keep = 0; int iv = -1;
      if (r < nr) {
        int i = g_freeRows[cur][r];
        iv = i;
        int j = g_rowBestJ[i];
        u64 cm = g_colMin[cur][j];
        if ((int)(unsigned)(cm & 0xffffffffull) == i) g_rowMatch[i] = j;
        else keep = 1;
      }
      u64 bm = __ballot(keep);
      int pre = __popcll(bm & ((1ull << lane) - 1ull));
      if (lane == 0) s_wc[wv] = __popcll(bm);
      __syncthreads();
      int off = 0, tot = 0;
#pragma unroll
      for (int w = 0; w < 8; ++w) { off += (w < wv) ? s_wc[w] : 0; tot += s_wc[w]; }
      if (keep) g_freeRows[nxt][s_base + off + pre] = iv;
      __syncthreads();
      if (tid == 0) s_base += tot;
      __syncthreads();
    }
    if (tid == 0) {
      int nnr = s_base;
      g_nr[nxt] = nnr;
      if (nnr <= TTHRESH || nnr >= nr) { g_finalCur = nxt; g_done = 1; }
    }
  } else {  // cols
    if (tid == 0) s_base = 0;
    __syncthreads();
    for (int start = 0; start < nc; start += SNT) {
      int c = start + tid;
      int keep = 0; int jv = -1;
      if (c < nc) {
        int j = g_freeCols[cur][c];
        jv = j;
        u64 cm = g_colMin[cur][j];
        int i2 = (int)(unsigned)(cm & 0xffffffffull);
        if (g_rowBestJ[i2] != j) keep = 1;
      }
      u64 bm = __ballot(keep);
      int pre = __popcll(bm & ((1ull << lane) - 1ull));
      if (lane == 0) s_wc[wv] = __popcll(bm);
      __syncthreads();
      int off = 0, tot = 0;
#pragma unroll
      for (int w = 0; w < 8; ++w) { off += (w < wv) ? s_wc[w] : 0; tot += s_wc[w]; }
      if (keep) g_freeCols[nxt][s_base + off + pre] = jv;
      __syncthreads();
      if (tid == 0) s_base += tot;
      __syncthreads();
    }
    if (tid == 0) g_nc[nxt] = s_base;
  }
}

// ================= gather: RECOMPUTE dense tail submatrix (whole grid) =======
__global__ void __launch_bounds__(SNT) k_gather(const float* __restrict__ x,
                                                const float* __restrict__ y) {
  const int fc = g_finalCur;
  const int mr = g_nr[fc], mc = g_nc[fc];
  if (mr <= 0 || mr > TCAP || mc <= 0 || mc > TCAP) return;
  const int tid = threadIdx.x, bid = blockIdx.x;
  for (int rr = bid; rr < mr; rr += SNB) {
    const int irow = g_freeRows[fc][rr];
    const float x2r = g_x2[irow];
    const float4* xb = reinterpret_cast<const float4*>(x + (size_t)irow * D);
    float* dst = g_tailC + (size_t)rr * TCAP;
    for (int c = tid; c < mc; c += SNT) {
      const int j = g_freeCols[fc][c];
      const float4* yb = reinterpret_cast<const float4*>(y + (size_t)j * D);
      float acc = 0.0f;
#pragma unroll
      for (int kc = 0; kc < 16; ++kc) {
        float4 xv = xb[kc];
        float4 yv = yb[kc];
        acc = fmaf(xv.x, yv.x, acc);
        acc = fmaf(xv.y, yv.y, acc);
        acc = fmaf(xv.z, yv.z, acc);
        acc = fmaf(xv.w, yv.w, acc);
      }
      dst[c] = cost_eval(acc, x2r, g_y2[j]);
    }
  }
}

// ================= tail: one block, dense matrix, per-wave rows =================
__global__ void __launch_bounds__(1024, 1) k_tail(int* __restrict__ out) {
  __shared__ int s_rpos[2][TCAP], s_cpos[2][TCAP];
  __shared__ int s_rbest[TCAP];
  __shared__ u64 s_cmin[TCAP];
  __shared__ int s_wc[16];
  const int tid = threadIdx.x;
  const int lane = tid & 63, wv = tid >> 6;

  const int fc = g_finalCur;
  int mr = g_nr[fc], mc = g_nc[fc];
  if (mr < 0 || mr > TCAP || mc < 0 || mc > TCAP) mr = 0;  // bail loudly (validation fails)
  for (int t = tid; t < mr; t += 1024) s_rpos[0][t] = t;
  for (int t = tid; t < mc; t += 1024) s_cpos[0][t] = t;
  __syncthreads();

  int tcur = 0;
  for (int round = 0; round < 2048 && mr > 0; ++round) {
    // ---- phase A: row bests, one row per wave ----
    const int nit = (mc + 63) >> 6;
    int cpv[16];
#pragma unroll
    for (int k = 0; k < 16; ++k) {
      int ci = (k << 6) + lane;
      cpv[k] = (k < nit && ci < mc) ? s_cpos[tcur][ci] : 0;
    }
    for (int rr = wv; rr < mr; rr += 16) {
      const int rp = s_rpos[tcur][rr];
      const float* rowp = g_tailC + (size_t)rp * TCAP;
      u64 best = ~0ull;
#pragma unroll
      for (int k = 0; k < 16; ++k) {
        if (k < nit) {
          int ci = (k << 6) + lane;
          if (ci < mc) {
            float cost = rowp[cpv[k]];
            u64 key = (((u64)__float_as_uint(cost)) << 32) | (unsigned)ci;  // col position
            best = (key < best) ? key : best;
          }
        }
      }
#pragma unroll
      for (int d = 32; d > 0; d >>= 1) {
        u64 o = shfl_down_u64(best, d);
        best = (o < best) ? o : best;
      }
      if (lane == 0) s_rbest[rr] = (int)(best & 0xffffffffull);
    }
    __syncthreads();
    // ---- phase B: col mins, one col per thread (mc <= 1024 = blockDim) ----
    if (tid < mc) {
      const int cp = s_cpos[tcur][tid];
      const float* colp = g_tailC + cp;
      u64 best = ~0ull;
      int r = 0;
      for (; r + 4 <= mr; r += 4) {
#pragma unroll
        for (int q = 0; q < 4; ++q) {
          int rp = s_rpos[tcur][r + q];
          float cost = colp[(size_t)rp * TCAP];
          u64 key = (((u64)__float_as_uint(cost)) << 32) | (unsigned)(r + q);  // row position
          best = (key < best) ? key : best;
        }
      }
      for (; r < mr; ++r) {
        int rp = s_rpos[tcur][r];
        float cost = colp[(size_t)rp * TCAP];
        u64 key = (((u64)__float_as_uint(cost)) << 32) | (unsigned)r;
        best = (key < best) ? key : best;
      }
      s_cmin[tid] = best;
    }
    __syncthreads();
    // ---- match rows + compact ----
    int keep = 0;
    if (tid < mr) {
      int q = s_rbest[tid];
      if ((int)(unsigned)(s_cmin[q] & 0xffffffffull) == tid) {
        g_rowMatch[g_freeRows[fc][s_rpos[tcur][tid]]] = g_freeCols[fc][s_cpos[tcur][q]];
      } else keep = 1;
    }
    u64 bm = __ballot(keep);
    int pre = __popcll(bm & ((1ull << lane) - 1ull));
    if (lane == 0) s_wc[wv] = __popcll(bm);
    __syncthreads();
    int off = 0, tot = 0;
#pragma unroll
    for (int w = 0; w < 16; ++w) { off += (w < wv) ? s_wc[w] : 0; tot += s_wc[w]; }
    if (keep) s_rpos[tcur ^ 1][off + pre] = s_rpos[tcur][tid];
    int newmr = tot;
    __syncthreads();
    // ---- compact cols ----
    int keepc = 0;
    if (tid < mc) {
      int r2 = (int)(unsigned)(s_cmin[tid] & 0xffffffffull);
      if (s_rbest[r2] != tid) keepc = 1;
    }
    u64 bm2 = __ballot(keepc);
    int pre2 = __popcll(bm2 & ((1ull << lane) - 1ull));
    if (lane == 0) s_wc[wv] = __popcll(bm2);
    __syncthreads();
    int off2 = 0, tot2 = 0;
#pragma unroll
    for (int w = 0; w < 16; ++w) { off2 += (w < wv) ? s_wc[w] : 0; tot2 += s_wc[w]; }
    if (keepc) s_cpos[tcur ^ 1][off2 + pre2] = s_cpos[tcur][tid];
    __syncthreads();
    if (newmr >= mr) break;  // safety (cannot happen mathematically)
    mr = newmr; mc = tot2; tcur ^= 1;
  }
  __syncthreads();
  for (int i = tid; i < N; i += 1024) out[i] = g_rowMatch[i];
}

extern "C" void kernel_launch(void* const* d_in, const int* in_sizes, int n_in,
                              void* d_out, int out_size, void* d_ws, size_t ws_size,
                              hipStream_t stream) {
  const float* x = (const float*)d_in[0];
  const float* y = (const float*)d_in[1];
  int* out = (int*)d_out;
  k_init<<<16, 256, 0, stream>>>(x, y);
  k_scan0<<<512, SNT, 0, stream>>>(x, y);
  k_match<<<SNB, SNT, 0, stream>>>(0);
  for (int r = 1; r <= RPAIRS; ++r) {
    k_scanN<<<SNB, SNT, 0, stream>>>(x, y, r);
    k_match<<<SNB, SNT, 0, stream>>>(r);
  }
  k_gather<<<SNB, SNT, 0, stream>>>(x, y);
  k_tail<<<1, 1024, 0, stream>>>(out);
  (void)in_sizes; (void)n_in; (void)out_size; (void)d_ws; (void)ws_size;
}

// Round 9
// 1136.136 us; speedup vs baseline: 1.3012x; 1.3012x over previous
//
#include <hip/hip_runtime.h>

#define N 4096
#define D 64
#define TCAP 1024
#define TTHRESH 96
#define SNB 256
#define SNT 512
#define RPAIRS 12

typedef unsigned long long u64;

// ---- persistent device state (no full cost matrix: costs are recomputed) ----
__device__ float g_tailC[(size_t)TCAP * TCAP]; // 4 MB dense tail matrix
__device__ float g_x2[N], g_y2[N];
__device__ int   g_rowMatch[N];
__device__ int   g_freeRows[2][N];
__device__ int   g_freeCols[2][N];
__device__ int   g_rowBestJ[N];
__device__ u64   g_colMin[2][N];
__device__ int   g_nr[2], g_nc[2];
__device__ int   g_done, g_finalCur;

__device__ inline u64 shfl_down_u64(u64 v, int d) {
  unsigned lo = (unsigned)(v & 0xffffffffull);
  unsigned hi = (unsigned)(v >> 32);
  lo = __shfl_down(lo, d, 64);
  hi = __shfl_down(hi, d, 64);
  return ((u64)hi << 32) | (u64)lo;
}

// 512-thread (8-wave) block min-reduce of per-thread best[r], r < rows <= 8.
// Result for row r in s_part[128 + r].
__device__ inline void block_rowmin_reduce8(u64* best, int rows, u64* s_part) {
  const int tid = threadIdx.x;
  const int lane = tid & 63;
  const int wv = tid >> 6;
#pragma unroll
  for (int r = 0; r < 8; ++r) {
    if (r < rows) {
      u64 v = best[r];
#pragma unroll
      for (int d = 32; d > 0; d >>= 1) {
        u64 o = shfl_down_u64(v, d);
        v = (o < v) ? o : v;
      }
      if (lane == 0) s_part[r * 8 + wv] = v;
    }
  }
  __syncthreads();
  if (tid < rows) {
    u64 mn = s_part[tid * 8];
#pragma unroll
    for (int w = 1; w < 8; ++w) {
      u64 o = s_part[tid * 8 + w];
      mn = (o < mn) ? o : mn;
    }
    s_part[128 + tid] = mn;
  }
}

// Exact cost chain (identical in every phase): kc-ascending fmaf x/y/z/w,
// then fl(fl(x2+y2) - 2*acc), clamp, sqrt.
__device__ inline float cost_eval(float acc, float x2r, float y2j) {
  float t = __fadd_rn(x2r, y2j);
  float sq = __fsub_rn(t, __fmul_rn(2.0f, acc));
  sq = fmaxf(sq, 0.0f);
  return __fsqrt_rn(sq);
}

// ================= init: x2/y2 + state reset =================
__global__ void __launch_bounds__(256) k_init(const float* __restrict__ x,
                                              const float* __restrict__ y) {
  const int i = blockIdx.x * 256 + threadIdx.x;  // grid = 16 blocks -> 4096
  // numpy pairwise_sum order for n=64: 8 accumulators, then
  // ((r0+r1)+(r2+r3)) + ((r4+r5)+(r6+r7)). No FMA contraction.
  const float* xr = x + (size_t)i * D;
  const float* yr = y + (size_t)i * D;
  float qx[8], qy[8];
#pragma unroll
  for (int j = 0; j < 8; ++j) {
    float v = xr[j]; qx[j] = __fmul_rn(v, v);
    float w = yr[j]; qy[j] = __fmul_rn(w, w);
  }
#pragma unroll
  for (int m = 8; m < D; m += 8) {
#pragma unroll
    for (int j = 0; j < 8; ++j) {
      float v = xr[m + j]; qx[j] = __fadd_rn(qx[j], __fmul_rn(v, v));
      float w = yr[m + j]; qy[j] = __fadd_rn(qy[j], __fmul_rn(w, w));
    }
  }
  g_x2[i] = __fadd_rn(__fadd_rn(__fadd_rn(qx[0], qx[1]), __fadd_rn(qx[2], qx[3])),
                      __fadd_rn(__fadd_rn(qx[4], qx[5]), __fadd_rn(qx[6], qx[7])));
  g_y2[i] = __fadd_rn(__fadd_rn(__fadd_rn(qy[0], qy[1]), __fadd_rn(qy[2], qy[3])),
                      __fadd_rn(__fadd_rn(qy[4], qy[5]), __fadd_rn(qy[6], qy[7])));
  g_rowMatch[i] = -1;
  g_freeRows[0][i] = i;
  g_freeCols[0][i] = i;
  g_colMin[0][i] = ~0ull;
  g_colMin[1][i] = ~0ull;
  if (i == 0) {
    g_nr[0] = N; g_nc[0] = N; g_nr[1] = 0; g_nc[1] = 0;
    g_done = 0;
    g_finalCur = ((RPAIRS & 1) ^ 1);  // fallback parity if g_done never fires
  }
}

// ================= round 0: cost recompute + row/col minima =================
// 8 rows x 2 cols per thread, 4 column passes. Register demand ~80 VGPRs:
// must stay under the 128-reg cap (the allocator refuses to exceed it and
// spills instead — r6-r8 PMC showed 40-100 MB/dispatch scratch traffic).
__global__ void __launch_bounds__(SNT) k_scan0(const float* __restrict__ x,
                                               const float* __restrict__ y) {
  __shared__ u64 s_part[128 + 16];
  const int tid = threadIdx.x;
  const int r0 = blockIdx.x << 3;  // 512 blocks x 8 rows

  float x2r[8];
#pragma unroll
  for (int r = 0; r < 8; ++r) x2r[r] = g_x2[r0 + r];
  u64 best[8];
#pragma unroll
  for (int r = 0; r < 8; ++r) best[r] = ~0ull;

#pragma unroll
  for (int q = 0; q < 4; ++q) {
    const int c0 = tid + (q << 10);  // col pair {c0, c0+512}
    float acc[8][2];
#pragma unroll
    for (int r = 0; r < 8; ++r) { acc[r][0] = 0.0f; acc[r][1] = 0.0f; }

    const float4* yb0 = reinterpret_cast<const float4*>(y + (size_t)c0 * D);
    const float4* yb1 = reinterpret_cast<const float4*>(y + (size_t)(c0 + 512) * D);
#pragma unroll
    for (int kc = 0; kc < 16; ++kc) {
      float4 yv0 = yb0[kc], yv1 = yb1[kc];
#pragma unroll
      for (int r = 0; r < 8; ++r) {
        float4 xv = reinterpret_cast<const float4*>(x + (size_t)(r0 + r) * D)[kc];  // uniform -> s_load
        acc[r][0] = fmaf(xv.x, yv0.x, acc[r][0]);
        acc[r][0] = fmaf(xv.y, yv0.y, acc[r][0]);
        acc[r][0] = fmaf(xv.z, yv0.z, acc[r][0]);
        acc[r][0] = fmaf(xv.w, yv0.w, acc[r][0]);
        acc[r][1] = fmaf(xv.x, yv1.x, acc[r][1]);
        acc[r][1] = fmaf(xv.y, yv1.y, acc[r][1]);
        acc[r][1] = fmaf(xv.z, yv1.z, acc[r][1]);
        acc[r][1] = fmaf(xv.w, yv1.w, acc[r][1]);
      }
    }
#pragma unroll
    for (int k = 0; k < 2; ++k) {
      const int c = c0 + (k << 9);
      const float y2j = g_y2[c];
      u64 ckey = ~0ull;
#pragma unroll
      for (int r = 0; r < 8; ++r) {
        float cost = cost_eval(acc[r][k], x2r[r], y2j);
        u64 cb = ((u64)__float_as_uint(cost)) << 32;
        u64 rk = cb | (unsigned)c;
        best[r] = (rk < best[r]) ? rk : best[r];
        u64 ck = cb | (unsigned)(r0 + r);
        ckey = (ck < ckey) ? ck : ckey;
      }
      u64 curv = g_colMin[0][c];  // stale reads only ever too-high: safe filter
      if (ckey < curv) atomicMin((unsigned long long*)&g_colMin[0][c], ckey);
    }
  }

  block_rowmin_reduce8(best, 8, s_part);
  if (tid < 8) g_rowBestJ[r0 + tid] = (int)(s_part[128 + tid] & 0xffffffffull);
}

// ================= rounds >= 1: recompute scan over free rows/cols ===========
// 8-row groups (row indices scalarized via readfirstlane -> x loads become
// SMEM), 2-col tile, group-stride loop.
__global__ void __launch_bounds__(SNT) k_scanN(const float* __restrict__ x,
                                               const float* __restrict__ y, int round) {
  if (g_done) return;
  const int cur = round & 1;
  const int nr = g_nr[cur], nc = g_nc[cur];
  const int tid = threadIdx.x, bid = blockIdx.x;
  const int ngroups = (nr + 7) >> 3;
  __shared__ u64 s_part[128 + 16];
  __shared__ int s_irow[8];
  const int j0 = g_freeCols[cur][0];

  for (int g = bid; g < ngroups; g += SNB) {
    __syncthreads();  // protect s_irow/s_part reuse across group iterations
    const int r0 = g << 3;
    const int rows = min(8, nr - r0);
    if (tid < 8) {
      int rr = (tid < rows) ? (r0 + tid) : r0;
      s_irow[tid] = g_freeRows[cur][rr];
    }
    __syncthreads();

    int ir[8]; float x2r[8];
#pragma unroll
    for (int r = 0; r < 8; ++r) {
      ir[r] = __builtin_amdgcn_readfirstlane(s_irow[r]);  // wave-uniform -> scalar x loads
      x2r[r] = g_x2[ir[r]];
    }
    u64 best[8];
#pragma unroll
    for (int r = 0; r < 8; ++r) best[r] = ~0ull;

    for (int cbase = tid; cbase < nc; cbase += (SNT << 1)) {
      int jj[2];
#pragma unroll
      for (int k = 0; k < 2; ++k) {
        int c = cbase + (k << 9);
        jj[k] = (c < nc) ? g_freeCols[cur][c] : j0;  // pad with valid col, masked later
      }
      float acc[8][2];
#pragma unroll
      for (int r = 0; r < 8; ++r) { acc[r][0] = 0.0f; acc[r][1] = 0.0f; }

      const float4* yb0 = reinterpret_cast<const float4*>(y + (size_t)jj[0] * D);
      const float4* yb1 = reinterpret_cast<const float4*>(y + (size_t)jj[1] * D);
#pragma unroll
      for (int kc = 0; kc < 16; ++kc) {
        float4 yv0 = yb0[kc], yv1 = yb1[kc];
#pragma unroll
        for (int r = 0; r < 8; ++r) {
          float4 xv = reinterpret_cast<const float4*>(x + (size_t)ir[r] * D)[kc];  // scalar
          acc[r][0] = fmaf(xv.x, yv0.x, acc[r][0]);
          acc[r][0] = fmaf(xv.y, yv0.y, acc[r][0]);
          acc[r][0] = fmaf(xv.z, yv0.z, acc[r][0]);
          acc[r][0] = fmaf(xv.w, yv0.w, acc[r][0]);
          acc[r][1] = fmaf(xv.x, yv1.x, acc[r][1]);
          acc[r][1] = fmaf(xv.y, yv1.y, acc[r][1]);
          acc[r][1] = fmaf(xv.z, yv1.z, acc[r][1]);
          acc[r][1] = fmaf(xv.w, yv1.w, acc[r][1]);
        }
      }
#pragma unroll
      for (int k = 0; k < 2; ++k) {
        if (cbase + (k << 9) < nc) {
          const int j = jj[k];
          const float y2j = g_y2[j];
          u64 ckey = ~0ull;
#pragma unroll
          for (int r = 0; r < 8; ++r) {
            if (r < rows) {
              float cost = cost_eval(acc[r][k], x2r[r], y2j);
              u64 cb = ((u64)__float_as_uint(cost)) << 32;
              u64 rk = cb | (unsigned)j;
              best[r] = (rk < best[r]) ? rk : best[r];
              u64 ck = cb | (unsigned)ir[r];
              ckey = (ck < ckey) ? ck : ckey;
            }
          }
          u64 curv = g_colMin[cur][j];
          if (ckey < curv) atomicMin((unsigned long long*)&g_colMin[cur][j], ckey);
        }
      }
    }

    block_rowmin_reduce8(best, rows, s_part);
    if (tid < rows) g_rowBestJ[s_irow[tid]] = (int)(s_part[128 + tid] & 0xffffffffull);
  }
}

// ================= match + rebuild free lists =================
__global__ void __launch_bounds__(SNT) k_match(int round) {
  if (g_done) return;
  const int cur = round & 1, nxt = cur ^ 1;
  const int tid = threadIdx.x, bid = blockIdx.x;
  const int nr = g_nr[cur], nc = g_nc[cur];
  __shared__ int s_wc[8];
  __shared__ int s_base;

  if (bid >= 2) {  // reset colMin buffer for round+1
    for (int t = (bid - 2) * SNT + tid; t < N; t += (SNB - 2) * SNT)
      g_colMin[nxt][t] = ~0ull;
    return;
  }

  const int lane = tid & 63, wv = tid >> 6;
  if (bid == 0) {  // rows: write matches + ordered compaction
    if (tid == 0) s_base = 0;
    __syncthreads();
    for (int start = 0; start < nr; start += SNT) {
      int r = start + tid;
      int keep = 0; int iv = -1;
      if (r < nr) {
        int i = g_freeRows[cur][r];
        iv = i;
        int j = g_rowBestJ[i];
        u64 cm = g_colMin[cur][j];
        if ((int)(unsigned)(cm & 0xffffffffull) == i) g_rowMatch[i] = j;
        else keep = 1;
      }
      u64 bm = __ballot(keep);
      int pre = __popcll(bm & ((1ull << lane) - 1ull));
      if (lane == 0) s_wc[wv] = __popcll(bm);
      __syncthreads();
      int off = 0, tot = 0;
#pragma unroll
      for (int w = 0; w < 8; ++w) { off += (w < wv) ? s_wc[w] : 0; tot += s_wc[w]; }
      if (keep) g_freeRows[nxt][s_base + off + pre] = iv;
      __syncthreads();
      if (tid == 0) s_base += tot;
      __syncthreads();
    }
    if (tid == 0) {
      int nnr = s_base;
      g_nr[nxt] = nnr;
      if (nnr <= TTHRESH || nnr >= nr) { g_finalCur = nxt; g_done = 1; }
    }
  } else {  // cols
    if (tid == 0) s_base = 0;
    __syncthreads();
    for (int start = 0; start < nc; start += SNT) {
      int c = start + tid;
      int keep = 0; int jv = -1;
      if (c < nc) {
        int j = g_freeCols[cur][c];
        jv = j;
        u64 cm = g_colMin[cur][j];
        int i2 = (int)(unsigned)(cm & 0xffffffffull);
        if (g_rowBestJ[i2] != j) keep = 1;
      }
      u64 bm = __ballot(keep);
      int pre = __popcll(bm & ((1ull << lane) - 1ull));
      if (lane == 0) s_wc[wv] = __popcll(bm);
      __syncthreads();
      int off = 0, tot = 0;
#pragma unroll
      for (int w = 0; w < 8; ++w) { off += (w < wv) ? s_wc[w] : 0; tot += s_wc[w]; }
      if (keep) g_freeCols[nxt][s_base + off + pre] = jv;
      __syncthreads();
      if (tid == 0) s_base += tot;
      __syncthreads();
    }
    if (tid == 0) g_nc[nxt] = s_base;
  }
}

// ================= gather: RECOMPUTE dense tail submatrix (whole grid) =======
__global__ void __launch_bounds__(SNT) k_gather(const float* __restrict__ x,
                                                const float* __restrict__ y) {
  const int fc = g_finalCur;
  const int mr = g_nr[fc], mc = g_nc[fc];
  if (mr <= 0 || mr > TCAP || mc <= 0 || mc > TCAP) return;
  const int tid = threadIdx.x, bid = blockIdx.x;
  for (int rr = bid; rr < mr; rr += SNB) {
    const int irow = g_freeRows[fc][rr];
    const float x2r = g_x2[irow];
    const float4* xb = reinterpret_cast<const float4*>(x + (size_t)irow * D);
    float* dst = g_tailC + (size_t)rr * TCAP;
    for (int c = tid; c < mc; c += SNT) {
      const int j = g_freeCols[fc][c];
      const float4* yb = reinterpret_cast<const float4*>(y + (size_t)j * D);
      float acc = 0.0f;
#pragma unroll
      for (int kc = 0; kc < 16; ++kc) {
        float4 xv = xb[kc];
        float4 yv = yb[kc];
        acc = fmaf(xv.x, yv.x, acc);
        acc = fmaf(xv.y, yv.y, acc);
        acc = fmaf(xv.z, yv.z, acc);
        acc = fmaf(xv.w, yv.w, acc);
      }
      dst[c] = cost_eval(acc, x2r, g_y2[j]);
    }
  }
}

// ================= tail: one block, dense matrix, per-wave rows =================
__global__ void __launch_bounds__(1024, 1) k_tail(int* __restrict__ out) {
  __shared__ int s_rpos[2][TCAP], s_cpos[2][TCAP];
  __shared__ int s_rbest[TCAP];
  __shared__ u64 s_cmin[TCAP];
  __shared__ int s_wc[16];
  const int tid = threadIdx.x;
  const int lane = tid & 63, wv = tid >> 6;

  const int fc = g_finalCur;
  int mr = g_nr[fc], mc = g_nc[fc];
  if (mr < 0 || mr > TCAP || mc < 0 || mc > TCAP) mr = 0;  // bail loudly (validation fails)
  for (int t = tid; t < mr; t += 1024) s_rpos[0][t] = t;
  for (int t = tid; t < mc; t += 1024) s_cpos[0][t] = t;
  __syncthreads();

  int tcur = 0;
  for (int round = 0; round < 2048 && mr > 0; ++round) {
    // ---- phase A: row bests, one row per wave ----
    const int nit = (mc + 63) >> 6;
    int cpv[16];
#pragma unroll
    for (int k = 0; k < 16; ++k) {
      int ci = (k << 6) + lane;
      cpv[k] = (k < nit && ci < mc) ? s_cpos[tcur][ci] : 0;
    }
    for (int rr = wv; rr < mr; rr += 16) {
      const int rp = s_rpos[tcur][rr];
      const float* rowp = g_tailC + (size_t)rp * TCAP;
      u64 best = ~0ull;
#pragma unroll
      for (int k = 0; k < 16; ++k) {
        if (k < nit) {
          int ci = (k << 6) + lane;
          if (ci < mc) {
            float cost = rowp[cpv[k]];
            u64 key = (((u64)__float_as_uint(cost)) << 32) | (unsigned)ci;  // col position
            best = (key < best) ? key : best;
          }
        }
      }
#pragma unroll
      for (int d = 32; d > 0; d >>= 1) {
        u64 o = shfl_down_u64(best, d);
        best = (o < best) ? o : best;
      }
      if (lane == 0) s_rbest[rr] = (int)(best & 0xffffffffull);
    }
    __syncthreads();
    // ---- phase B: col mins, one col per thread (mc <= 1024 = blockDim) ----
    if (tid < mc) {
      const int cp = s_cpos[tcur][tid];
      const float* colp = g_tailC + cp;
      u64 best = ~0ull;
      int r = 0;
      for (; r + 4 <= mr; r += 4) {
#pragma unroll
        for (int q = 0; q < 4; ++q) {
          int rp = s_rpos[tcur][r + q];
          float cost = colp[(size_t)rp * TCAP];
          u64 key = (((u64)__float_as_uint(cost)) << 32) | (unsigned)(r + q);  // row position
          best = (key < best) ? key : best;
        }
      }
      for (; r < mr; ++r) {
        int rp = s_rpos[tcur][r];
        float cost = colp[(size_t)rp * TCAP];
        u64 key = (((u64)__float_as_uint(cost)) << 32) | (unsigned)r;
        best = (key < best) ? key : best;
      }
      s_cmin[tid] = best;
    }
    __syncthreads();
    // ---- match rows + compact ----
    int keep = 0;
    if (tid < mr) {
      int q = s_rbest[tid];
      if ((int)(unsigned)(s_cmin[q] & 0xffffffffull) == tid) {
        g_rowMatch[g_freeRows[fc][s_rpos[tcur][tid]]] = g_freeCols[fc][s_cpos[tcur][q]];
      } else keep = 1;
    }
    u64 bm = __ballot(keep);
    int pre = __popcll(bm & ((1ull << lane) - 1ull));
    if (lane == 0) s_wc[wv] = __popcll(bm);
    __syncthreads();
    int off = 0, tot = 0;
#pragma unroll
    for (int w = 0; w < 16; ++w) { off += (w < wv) ? s_wc[w] : 0; tot += s_wc[w]; }
    if (keep) s_rpos[tcur ^ 1][off + pre] = s_rpos[tcur][tid];
    int newmr = tot;
    __syncthreads();
    // ---- compact cols ----
    int keepc = 0;
    if (tid < mc) {
      int r2 = (int)(unsigned)(s_cmin[tid] & 0xffffffffull);
      if (s_rbest[r2] != tid) keepc = 1;
    }
    u64 bm2 = __ballot(keepc);
    int pre2 = __popcll(bm2 & ((1ull << lane) - 1ull));
    if (lane == 0) s_wc[wv] = __popcll(bm2);
    __syncthreads();
    int off2 = 0, tot2 = 0;
#pragma unroll
    for (int w = 0; w < 16; ++w) { off2 += (w < wv) ? s_wc[w] : 0; tot2 += s_wc[w]; }
    if (keepc) s_cpos[tcur ^ 1][off2 + pre2] = s_cpos[tcur][tid];
    __syncthreads();
    if (newmr >= mr) break;  // safety (cannot happen mathematically)
    mr = newmr; mc = tot2; tcur ^= 1;
  }
  __syncthreads();
  for (int i = tid; i < N; i += 1024) out[i] = g_rowMatch[i];
}

extern "C" void kernel_launch(void* const* d_in, const int* in_sizes, int n_in,
                              void* d_out, int out_size, void* d_ws, size_t ws_size,
                              hipStream_t stream) {
  const float* x = (const float*)d_in[0];
  const float* y = (const float*)d_in[1];
  int* out = (int*)d_out;
  k_init<<<16, 256, 0, stream>>>(x, y);
  k_scan0<<<512, SNT, 0, stream>>>(x, y);
  k_match<<<SNB, SNT, 0, stream>>>(0);
  for (int r = 1; r <= RPAIRS; ++r) {
    k_scanN<<<SNB, SNT, 0, stream>>>(x, y, r);
    k_match<<<SNB, SNT, 0, stream>>>(r);
  }
  k_gather<<<SNB, SNT, 0, stream>>>(x, y);
  k_tail<<<1, 1024, 0, stream>>>(out);
  (void)in_sizes; (void)n_in; (void)out_size; (void)d_ws; (void)ws_size;
}